// Round 14
// baseline (222.460 us; speedup 1.0000x reference)
//
#include <hip/hip_runtime.h>
#include <hip/hip_bf16.h>
#include <hip/hip_cooperative_groups.h>

namespace cg = cooperative_groups;

// BinaryReflectanceGate: pointwise MLP (4->16->16, relu) -> segment max over
// sorted batch ids [B=64] -> 2-logit gate + gumbel softmax -> scale reflectance.
//
// Round-14: SINGLE COOPERATIVE KERNEL (3 kernels -> 1, two grid.sync()s).
//   Phase 1: r10's proven MLP+segmax body (straight-line phase-split do_chunk,
//            rolling prefetch), 512 blocks x 4 waves x 2048 pts. Block partials
//            -> pv/pid (global); block's own {idA,idB,bpos} stay in LDS.
//   Phase 2: blocks 0..63 reduce all 1024 partial entries for their segment,
//            compute gate[b] = sigmoid(l1-l0) (gumbel-softmax col 1, TAU=1).
//   Phase 3: each block scales its own 8192 points using LDS-held ids + gate
//            from ws. No recs traffic, no batch re-read, no launch gaps.
//   Co-residency: 512 blocks = 2/CU at 256 thr, VGPR ~52 -> guaranteed.
//
// MFMA layout facts (HW-verified r4, absmax 0.0039):
//   C/D: col=lane&15, row=(lane>>4)*4+reg. Lane l owns points 4l..4l+3 of each
//   256-pt chunk (pos floats 12l..12l+11 = 3 aligned float4s + refl float4).
//   In MFMA (j,t), lanes with g==t feed their j-th point; column c's point id
//   = sb + 4*(16t+c) + j (closed form, used for straddle select).

#define N_PTS 4194304
#define NB 64
#define NH 16
#define WPB 4                       // waves per block
#define SITERS 8                    // 256-pt chunks per wave
#define PTW (256 * SITERS)          // 2048 points per wave
#define PPB (WPB * PTW)             // 8192 points per block
#define NBLK (N_PTS / PPB)          // 512 blocks (2/CU -> coop-safe)
#define NENT (NBLK * 2)             // 1024 partial entries

typedef __attribute__((ext_vector_type(8))) short bf16x8;
typedef __attribute__((ext_vector_type(4))) float f32x4;
union U8 { bf16x8 v; unsigned u[4]; unsigned short s[8]; };

__device__ __forceinline__ unsigned pk2(float a, float b) {
    float2 t; t.x = a; t.y = b;
    __hip_bfloat162 r = __float22bfloat162_rn(t);
    unsigned u;
    __builtin_memcpy(&u, &r, sizeof(u));
    return u;
}
__device__ __forceinline__ unsigned short f2bf(float x) {   // RNE, setup only
    unsigned u = __float_as_uint(x);
    u = u + 0x7fffu + ((u >> 16) & 1u);
    return (unsigned short)(u >> 16);
}

// One 256-pt chunk: lane's 4 points through both layers, phase-split for ILP.
template<bool SLOW>
__device__ __forceinline__ void do_chunk(
    const float4& q0, const float4& q1, const float4& q2, const float4& rr,
    int sb, int g, int col, int bposw,
    const U8& A1, const U8& A2, const f32x4& c1, const f32x4& c2,
    f32x4& accA, f32x4& accB)
{
    const float f[4][4] = {{q0.x, q0.y, q0.z, rr.x},
                           {q0.w, q1.x, q1.y, rr.y},
                           {q1.z, q1.w, q2.x, rr.z},
                           {q2.y, q2.z, q2.w, rr.w}};
#pragma unroll
    for (int j = 0; j < 4; ++j) {
        const unsigned F01 = pk2(f[j][0], f[j][1]);
        const unsigned F23 = pk2(f[j][2], f[j][3]);
        f32x4 d[4], h[4];                 // static-indexed (fully unrolled)
#pragma unroll
        for (int t = 0; t < 4; ++t) {     // phase 1: 4 independent MFMA1
            const bool mine = (g == t);
            U8 B;
            B.u[0] = mine ? F01 : 0u;
            B.u[1] = mine ? F23 : 0u;
            B.u[2] = 0u; B.u[3] = 0u;
            d[t] = __builtin_amdgcn_mfma_f32_16x16x32_bf16(A1.v, B.v, c1, 0, 0, 0);
        }
#pragma unroll
        for (int t = 0; t < 4; ++t) {     // phase 2+3: pack, 4 MFMA2
            U8 P;
            P.u[0] = pk2(fmaxf(d[t][0], 0.f), fmaxf(d[t][1], 0.f));
            P.u[1] = pk2(fmaxf(d[t][2], 0.f), fmaxf(d[t][3], 0.f));
            P.u[2] = 0u; P.u[3] = 0u;
            h[t] = __builtin_amdgcn_mfma_f32_16x16x32_bf16(A2.v, P.v, c2, 0, 0, 0);
        }
#pragma unroll
        for (int t = 0; t < 4; ++t) {     // phase 4: accumulate
            if (!SLOW) {
#pragma unroll
                for (int r = 0; r < 4; ++r) accA[r] = fmaxf(accA[r], h[t][r]);
            } else {
                const bool m = (sb + 4 * (16 * t + col) + j) < bposw;
#pragma unroll
                for (int r = 0; r < 4; ++r) {
                    accA[r] = fmaxf(accA[r], m ? h[t][r] : 0.f);
                    accB[r] = fmaxf(accB[r], m ? 0.f : h[t][r]);
                }
            }
        }
    }
}

// ---------------- fused cooperative kernel ----------------
__global__ __launch_bounds__(256, 2) void fused_kernel(
    const float* __restrict__ pos,    // [N,3]
    const float* __restrict__ refl,   // [N]
    const int*   __restrict__ batch,  // [N] sorted
    const float* __restrict__ W1, const float* __restrict__ b1,
    const float* __restrict__ W2, const float* __restrict__ b2,
    const float* __restrict__ Wg, const float* __restrict__ bg,
    const float* __restrict__ gum,    // gumbels [64,2]
    float* __restrict__ pv,           // ws [NENT,16]
    int*   __restrict__ pid,          // ws [NENT]
    float* __restrict__ gate,         // ws [64]
    float* __restrict__ out)          // [N]
{
    __shared__ float lv[WPB][2][NH];
    __shared__ int   li[WPB][2];
    __shared__ int   lbp[WPB];
    __shared__ int   bIdA, bIdB, bBp;
    __shared__ float s2[17][NH];      // phase-2 scratch

    const int lane = threadIdx.x & 63;
    const int wid  = threadIdx.x >> 6;
    const int col  = lane & 15;
    const int g    = lane >> 4;
    const int wb   = (blockIdx.x * WPB + wid) * PTW;

    // ======================= PHASE 1: MLP + segmax =======================
    U8 A1, A2;
#pragma unroll
    for (int e = 0; e < 4; ++e) {
        A1.s[e]     = f2bf(W1[e * NH + col]);
        A1.s[e + 4] = 0;
        A2.s[e]     = f2bf(W2[(4 * g + e) * NH + col]);
        A2.s[e + 4] = 0;
    }
    f32x4 c1, c2;
#pragma unroll
    for (int r = 0; r < 4; ++r) { c1[r] = b1[4 * g + r]; c2[r] = b2[4 * g + r]; }

    const int idA = batch[wb];
    const int idB = batch[wb + PTW - 1];
    const bool isSlow = (idA != idB);      // wave-uniform

    f32x4 accA = {0.f, 0.f, 0.f, 0.f};
    f32x4 accB = {0.f, 0.f, 0.f, 0.f};

    const float4* gp = (const float4*)(pos + (size_t)wb * 3);
    const float4* gr = (const float4*)(refl + wb);

    float4 q0 = gp[3 * lane + 0];
    float4 q1 = gp[3 * lane + 1];
    float4 q2 = gp[3 * lane + 2];
    float4 rr = gr[lane];

    if (!isSlow) {
        // ---- fast path: straight-line, rolling prefetch (r10, proven) ----
#pragma unroll
        for (int s = 0; s < SITERS; ++s) {
            float4 n0, n1, n2, nr;
            if (s + 1 < SITERS) {
                n0 = gp[(s + 1) * 192 + 3 * lane + 0];
                n1 = gp[(s + 1) * 192 + 3 * lane + 1];
                n2 = gp[(s + 1) * 192 + 3 * lane + 2];
                nr = gr[(s + 1) * 64 + lane];
            }
            do_chunk<false>(q0, q1, q2, rr, wb + s * 256, g, col, 0,
                            A1, A2, c1, c2, accA, accB);
            if (s + 1 < SITERS) { q0 = n0; q1 = n1; q2 = n2; rr = nr; }
        }
    } else {
        // ---- slow path (~63 waves): boundary scan, then select-accumulate
        int bposw = 0x7fffffff;
        for (int it = 0; it < PTW / 64; ++it) {
            const int idx = wb + it * 64 + lane;
            const unsigned long long mk = __ballot(batch[idx] != idA);
            if (mk) bposw = min(bposw, wb + it * 64 + (__ffsll((long long)mk) - 1));
        }
#pragma unroll
        for (int s = 0; s < SITERS; ++s) {
            float4 n0, n1, n2, nr;
            if (s + 1 < SITERS) {
                n0 = gp[(s + 1) * 192 + 3 * lane + 0];
                n1 = gp[(s + 1) * 192 + 3 * lane + 1];
                n2 = gp[(s + 1) * 192 + 3 * lane + 2];
                nr = gr[(s + 1) * 64 + lane];
            }
            do_chunk<true>(q0, q1, q2, rr, wb + s * 256, g, col, bposw,
                           A1, A2, c1, c2, accA, accB);
            if (s + 1 < SITERS) { q0 = n0; q1 = n1; q2 = n2; rr = nr; }
        }
        lbp[wid] = bposw;
    }

    // ---- wave reduce across the 16 columns ----
#pragma unroll
    for (int mk = 1; mk <= 8; mk <<= 1) {
#pragma unroll
        for (int r = 0; r < 4; ++r) {
            accA[r] = fmaxf(accA[r], __shfl_xor(accA[r], mk));
            accB[r] = fmaxf(accB[r], __shfl_xor(accB[r], mk));
        }
    }
    if (col == 0) {   // lanes 0,16,32,48 hold dims 4g..4g+3
        *reinterpret_cast<float4*>(&lv[wid][0][4 * g]) =
            make_float4(accA[0], accA[1], accA[2], accA[3]);
        *reinterpret_cast<float4*>(&lv[wid][1][4 * g]) =
            make_float4(accB[0], accB[1], accB[2], accB[3]);
    }
    if (lane == 0) {
        li[wid][0] = idA; li[wid][1] = idB;
        if (!isSlow) lbp[wid] = 0x7fffffff;
    }
    __syncthreads();

    // ---- block combine (<=2 segments per 8192-pt block) ----
    if (threadIdx.x < NH) {
        const int d   = threadIdx.x;
        const int ida = li[0][0];
        const int idb = li[WPB - 1][1];
        float mA = 0.f, mB = 0.f;
#pragma unroll
        for (int s = 0; s < WPB; ++s)
#pragma unroll
            for (int hh = 0; hh < 2; ++hh) {
                const float val = lv[s][hh][d];
                if (li[s][hh] == ida) mA = fmaxf(mA, val);
                else                  mB = fmaxf(mB, val);
            }
        pv[(blockIdx.x * 2 + 0) * NH + d] = mA;
        pv[(blockIdx.x * 2 + 1) * NH + d] = mB;
        if (d == 0) {
            pid[blockIdx.x * 2 + 0] = ida;
            pid[blockIdx.x * 2 + 1] = idb;
            int bp = 0x7fffffff;
#pragma unroll
            for (int s = 0; s < WPB; ++s) {
                if (li[s][0] != ida) bp = min(bp, (int)(blockIdx.x * PPB + s * PTW));
                else if (lbp[s] != 0x7fffffff) bp = min(bp, lbp[s]);
            }
            bIdA = ida; bIdB = idb; bBp = bp;   // stays in LDS for phase 3
        }
    }

    __threadfence();
    cg::this_grid().sync();

    // ======================= PHASE 2: gate (blocks 0..63) ================
    if (blockIdx.x < NB) {
        const int b   = blockIdx.x;
        const int d   = threadIdx.x & 15;
        const int grp = threadIdx.x >> 4;          // 16 groups
        float m = 0.f;
        for (int e = grp; e < NENT; e += 16)
            if (pid[e] == b) m = fmaxf(m, pv[e * NH + d]);
        s2[grp][d] = m;
        __syncthreads();
        if (threadIdx.x < NH) {
            float mx = 0.f;
#pragma unroll
            for (int gq = 0; gq < 16; ++gq) mx = fmaxf(mx, s2[gq][threadIdx.x]);
            s2[16][threadIdx.x] = mx;
        }
        __syncthreads();
        if (threadIdx.x == 0) {
            float l0 = bg[0] + gum[b * 2 + 0];
            float l1 = bg[1] + gum[b * 2 + 1];
#pragma unroll
            for (int k = 0; k < NH; ++k) {
                const float s = s2[16][k];
                l0 = fmaf(s, Wg[k * 2 + 0], l0);
                l1 = fmaf(s, Wg[k * 2 + 1], l1);
            }
            gate[b] = 1.f / (1.f + expf(-(l1 - l0)));   // softmax[:,1], TAU=1
        }
    }

    __threadfence();
    cg::this_grid().sync();

    // ======================= PHASE 3: scale own range ====================
    const float gA = gate[bIdA];
    const float gB = gate[bIdB];
    const int   bp = bBp;
    const size_t base = (size_t)blockIdx.x * PPB;
    const float4* r4 = (const float4*)(refl + base);
    float4*       o4 = (float4*)(out + base);
#pragma unroll
    for (int k = 0; k < PPB / 4 / 256; ++k) {      // 8 float4s per thread
        const int idx = k * 256 + threadIdx.x;
        const float4 rv = r4[idx];
        const int p0 = (int)base + idx * 4;
        float4 o;
        o.x = ((p0 + 0) < bp ? gA : gB) * rv.x;
        o.y = ((p0 + 1) < bp ? gA : gB) * rv.y;
        o.z = ((p0 + 2) < bp ? gA : gB) * rv.z;
        o.w = ((p0 + 3) < bp ? gA : gB) * rv.w;
        o4[idx] = o;
    }
}

extern "C" void kernel_launch(void* const* d_in, const int* in_sizes, int n_in,
                              void* d_out, int out_size, void* d_ws, size_t ws_size,
                              hipStream_t stream) {
    const float* pos   = (const float*)d_in[0];
    const float* refl  = (const float*)d_in[1];
    const int*   batch = (const int*)d_in[2];
    const float* gumb  = (const float*)d_in[3];
    const float* W1    = (const float*)d_in[4];
    const float* b1    = (const float*)d_in[5];
    const float* W2    = (const float*)d_in[6];
    const float* b2    = (const float*)d_in[7];
    const float* Wg    = (const float*)d_in[8];
    const float* bg    = (const float*)d_in[9];
    float* out = (float*)d_out;

    // ws layout: pv 64KB | pid 4KB | gate 256B
    float* pv   = (float*)d_ws;
    int*   pid  = (int*)((char*)d_ws + 65536);
    float* gate = (float*)((char*)d_ws + 65536 + 4096);

    void* args[] = {
        (void*)&pos, (void*)&refl, (void*)&batch,
        (void*)&W1, (void*)&b1, (void*)&W2, (void*)&b2,
        (void*)&Wg, (void*)&bg, (void*)&gumb,
        (void*)&pv, (void*)&pid, (void*)&gate, (void*)&out
    };
    (void)hipLaunchCooperativeKernel((void*)fused_kernel,
                                     dim3(NBLK), dim3(256), args, 0, stream);
}

// Round 15
// 38.876 us; speedup vs baseline: 5.7224x; 5.7224x over previous
//
#include <hip/hip_runtime.h>
#include <hip/hip_bf16.h>

// BinaryReflectanceGate: pointwise MLP (4->16->16, relu) -> segment max over
// sorted batch ids [B=64] -> 2-logit gate + gumbel softmax -> scale reflectance.
//
// Round-15 (r10 base = best 40.2us, two structural cuts):
//   A (mlp_segmax): r10's proven body + LDS weight staging (block-cooperative
//     coalesced load of W1/b1/W2/b2 -> LDS; kills 8 scattered global gathers
//     of serial latency per wave x 4096 waves). Writes pv/pid/recs.
//   B (gate_scale): stage2 REMOVED. Each of 4096 blocks: scan pid[2048]
//     (8KB coalesced, L2-hot) -> LDS list of entries matching its <=2 segment
//     ids (~70) -> LDS atomicMax segmax[2][16] -> 2 threads compute sigmoids
//     -> scale its 1024 points. No single-block serialization, one less launch.
//
// MFMA layout facts (HW-verified r4, absmax 0.0039):
//   C/D: col=lane&15, row=(lane>>4)*4+reg. Lane l owns points 4l..4l+3 of each
//   256-pt chunk (pos floats 12l..12l+11 = 3 aligned float4s + refl float4).
//   In MFMA (j,t), lanes with g==t feed their j-th point; column c's point id
//   = sb + 4*(16t+c) + j (closed form, used for straddle select).

#define N_PTS 4194304
#define NB 64
#define NH 16
#define WPB 4                       // waves per block
#define SITERS 4                    // 256-pt chunks per wave
#define PTW (256 * SITERS)          // 1024 points per wave
#define PPB (WPB * PTW)             // 4096 points per block
#define NBLK (N_PTS / PPB)          // 1024 blocks
#define NENT (NBLK * 2)             // 2048 partial entries

typedef __attribute__((ext_vector_type(8))) short bf16x8;
typedef __attribute__((ext_vector_type(4))) float f32x4;
union U8 { bf16x8 v; unsigned u[4]; unsigned short s[8]; };

struct Rec { int idA, idB, bpos; };

__device__ __forceinline__ unsigned pk2(float a, float b) {
    float2 t; t.x = a; t.y = b;
    __hip_bfloat162 r = __float22bfloat162_rn(t);
    unsigned u;
    __builtin_memcpy(&u, &r, sizeof(u));
    return u;
}
__device__ __forceinline__ unsigned short f2bf(float x) {   // RNE, setup only
    unsigned u = __float_as_uint(x);
    u = u + 0x7fffu + ((u >> 16) & 1u);
    return (unsigned short)(u >> 16);
}

// One 256-pt chunk: lane's 4 points through both layers, phase-split for ILP.
template<bool SLOW>
__device__ __forceinline__ void do_chunk(
    const float4& q0, const float4& q1, const float4& q2, const float4& rr,
    int sb, int g, int col, int bposw,
    const U8& A1, const U8& A2, const f32x4& c1, const f32x4& c2,
    f32x4& accA, f32x4& accB)
{
    const float f[4][4] = {{q0.x, q0.y, q0.z, rr.x},
                           {q0.w, q1.x, q1.y, rr.y},
                           {q1.z, q1.w, q2.x, rr.z},
                           {q2.y, q2.z, q2.w, rr.w}};
#pragma unroll
    for (int j = 0; j < 4; ++j) {
        const unsigned F01 = pk2(f[j][0], f[j][1]);
        const unsigned F23 = pk2(f[j][2], f[j][3]);
        f32x4 d[4], h[4];                 // static-indexed (fully unrolled)
#pragma unroll
        for (int t = 0; t < 4; ++t) {     // phase 1: 4 independent MFMA1
            const bool mine = (g == t);
            U8 B;
            B.u[0] = mine ? F01 : 0u;
            B.u[1] = mine ? F23 : 0u;
            B.u[2] = 0u; B.u[3] = 0u;
            d[t] = __builtin_amdgcn_mfma_f32_16x16x32_bf16(A1.v, B.v, c1, 0, 0, 0);
        }
#pragma unroll
        for (int t = 0; t < 4; ++t) {     // phase 2+3: pack, 4 MFMA2
            U8 P;
            P.u[0] = pk2(fmaxf(d[t][0], 0.f), fmaxf(d[t][1], 0.f));
            P.u[1] = pk2(fmaxf(d[t][2], 0.f), fmaxf(d[t][3], 0.f));
            P.u[2] = 0u; P.u[3] = 0u;
            h[t] = __builtin_amdgcn_mfma_f32_16x16x32_bf16(A2.v, P.v, c2, 0, 0, 0);
        }
#pragma unroll
        for (int t = 0; t < 4; ++t) {     // phase 4: accumulate
            if (!SLOW) {
#pragma unroll
                for (int r = 0; r < 4; ++r) accA[r] = fmaxf(accA[r], h[t][r]);
            } else {
                const bool m = (sb + 4 * (16 * t + col) + j) < bposw;
#pragma unroll
                for (int r = 0; r < 4; ++r) {
                    accA[r] = fmaxf(accA[r], m ? h[t][r] : 0.f);
                    accB[r] = fmaxf(accB[r], m ? 0.f : h[t][r]);
                }
            }
        }
    }
}

// ---------------- A: MLP + segment-max partials + records ----------------
__global__ __launch_bounds__(256, 4) void mlp_segmax_kernel(
    const float* __restrict__ pos,    // [N,3]
    const float* __restrict__ refl,   // [N]
    const int*   __restrict__ batch,  // [N] sorted
    const float* __restrict__ W1, const float* __restrict__ b1,
    const float* __restrict__ W2, const float* __restrict__ b2,
    float* __restrict__ pv,           // [NENT,16]
    int*   __restrict__ pid,          // [NENT]
    Rec*   __restrict__ recs)         // [NBLK]
{
    __shared__ float wlds[352];       // W1[64] | b1[16] | W2[256] | b2[16]
    __shared__ float lv[WPB][2][NH];
    __shared__ int   li[WPB][2];
    __shared__ int   lbp[WPB];

    const int tid  = threadIdx.x;
    const int lane = tid & 63;
    const int wid  = tid >> 6;
    const int col  = lane & 15;
    const int g    = lane >> 4;
    const int wb   = (blockIdx.x * WPB + wid) * PTW;

    // ---- block-cooperative coalesced weight staging ----
    if (tid < 64)  wlds[tid]        = W1[tid];
    if (tid < 16)  wlds[64 + tid]   = b1[tid];
    wlds[80 + tid] = W2[tid];        // 256 threads, 256 floats
    if (tid < 16)  wlds[336 + tid]  = b2[tid];
    __syncthreads();

    U8 A1, A2;
#pragma unroll
    for (int e = 0; e < 4; ++e) {
        A1.s[e]     = f2bf(wlds[e * NH + col]);
        A1.s[e + 4] = 0;
        A2.s[e]     = f2bf(wlds[80 + (4 * g + e) * NH + col]);
        A2.s[e + 4] = 0;
    }
    f32x4 c1, c2;
#pragma unroll
    for (int r = 0; r < 4; ++r) {
        c1[r] = wlds[64 + 4 * g + r];
        c2[r] = wlds[336 + 4 * g + r];
    }

    const int idA = batch[wb];
    const int idB = batch[wb + PTW - 1];
    const bool isSlow = (idA != idB);      // wave-uniform

    f32x4 accA = {0.f, 0.f, 0.f, 0.f};
    f32x4 accB = {0.f, 0.f, 0.f, 0.f};

    const float4* gp = (const float4*)(pos + (size_t)wb * 3);
    const float4* gr = (const float4*)(refl + wb);

    float4 q0 = gp[3 * lane + 0];
    float4 q1 = gp[3 * lane + 1];
    float4 q2 = gp[3 * lane + 2];
    float4 rr = gr[lane];

    if (!isSlow) {
        // ---- fast path: straight-line, rolling prefetch (r10, proven) ----
#pragma unroll
        for (int s = 0; s < SITERS; ++s) {
            float4 n0, n1, n2, nr;
            if (s + 1 < SITERS) {
                n0 = gp[(s + 1) * 192 + 3 * lane + 0];
                n1 = gp[(s + 1) * 192 + 3 * lane + 1];
                n2 = gp[(s + 1) * 192 + 3 * lane + 2];
                nr = gr[(s + 1) * 64 + lane];
            }
            do_chunk<false>(q0, q1, q2, rr, wb + s * 256, g, col, 0,
                            A1, A2, c1, c2, accA, accB);
            if (s + 1 < SITERS) { q0 = n0; q1 = n1; q2 = n2; rr = nr; }
        }
    } else {
        // ---- slow path (~63 waves): boundary scan, then select-accumulate
        int bposw = 0x7fffffff;
        for (int it = 0; it < PTW / 64; ++it) {
            const int idx = wb + it * 64 + lane;
            const unsigned long long mk = __ballot(batch[idx] != idA);
            if (mk) bposw = min(bposw, wb + it * 64 + (__ffsll((long long)mk) - 1));
        }
#pragma unroll
        for (int s = 0; s < SITERS; ++s) {
            float4 n0, n1, n2, nr;
            if (s + 1 < SITERS) {
                n0 = gp[(s + 1) * 192 + 3 * lane + 0];
                n1 = gp[(s + 1) * 192 + 3 * lane + 1];
                n2 = gp[(s + 1) * 192 + 3 * lane + 2];
                nr = gr[(s + 1) * 64 + lane];
            }
            do_chunk<true>(q0, q1, q2, rr, wb + s * 256, g, col, bposw,
                           A1, A2, c1, c2, accA, accB);
            if (s + 1 < SITERS) { q0 = n0; q1 = n1; q2 = n2; rr = nr; }
        }
        lbp[wid] = bposw;
    }

    // ---- wave reduce across the 16 columns ----
#pragma unroll
    for (int mk = 1; mk <= 8; mk <<= 1) {
#pragma unroll
        for (int r = 0; r < 4; ++r) {
            accA[r] = fmaxf(accA[r], __shfl_xor(accA[r], mk));
            accB[r] = fmaxf(accB[r], __shfl_xor(accB[r], mk));
        }
    }
    if (col == 0) {   // lanes 0,16,32,48 hold dims 4g..4g+3
        *reinterpret_cast<float4*>(&lv[wid][0][4 * g]) =
            make_float4(accA[0], accA[1], accA[2], accA[3]);
        *reinterpret_cast<float4*>(&lv[wid][1][4 * g]) =
            make_float4(accB[0], accB[1], accB[2], accB[3]);
    }
    if (lane == 0) {
        li[wid][0] = idA; li[wid][1] = idB;
        if (!isSlow) lbp[wid] = 0x7fffffff;
    }
    __syncthreads();

    // ---- block combine (<=2 segments per 4096-pt block) ----
    if (tid < NH) {
        const int d   = tid;
        const int ida = li[0][0];
        const int idb = li[WPB - 1][1];
        float mA = 0.f, mB = 0.f;
#pragma unroll
        for (int s = 0; s < WPB; ++s)
#pragma unroll
            for (int hh = 0; hh < 2; ++hh) {
                const float val = lv[s][hh][d];
                if (li[s][hh] == ida) mA = fmaxf(mA, val);
                else                  mB = fmaxf(mB, val);
            }
        pv[(blockIdx.x * 2 + 0) * NH + d] = mA;
        pv[(blockIdx.x * 2 + 1) * NH + d] = mB;
        if (d == 0) {
            pid[blockIdx.x * 2 + 0] = ida;
            pid[blockIdx.x * 2 + 1] = idb;
            int bp = 0x7fffffff;
#pragma unroll
            for (int s = 0; s < WPB; ++s) {
                if (li[s][0] != ida) bp = min(bp, (int)(blockIdx.x * PPB + s * PTW));
                else if (lbp[s] != 0x7fffffff) bp = min(bp, lbp[s]);
            }
            Rec r; r.idA = ida; r.idB = idb; r.bpos = bp;
            recs[blockIdx.x] = r;
        }
    }
}

// ---------------- B: fused gate + scale (stage2 eliminated) ----------------
__global__ __launch_bounds__(256) void gate_scale_kernel(
    const float* __restrict__ refl,
    const float* __restrict__ pv,     // [NENT,16]
    const int*   __restrict__ pid,    // [NENT]
    const Rec*   __restrict__ recs,   // [NBLK]
    const float* __restrict__ Wg, const float* __restrict__ bg,
    const float* __restrict__ gum,
    float* __restrict__ out)
{
    __shared__ unsigned smA[NH], smB[NH];
    __shared__ unsigned short list[128];
    __shared__ unsigned cnt;
    __shared__ float gAB[2];

    const int tid = threadIdx.x;
    const Rec rec = recs[blockIdx.x >> 2];     // 4 scale-blocks per A-block

    if (tid < NH) { smA[tid] = 0u; smB[tid] = 0u; }
    if (tid == 0) cnt = 0u;
    __syncthreads();

    // ---- scan pid (8KB, coalesced, L2-hot): collect matching entries ----
#pragma unroll
    for (int k = 0; k < NENT / 256; ++k) {
        const int e = k * 256 + tid;
        const int p = pid[e];
        const bool a = (p == rec.idA);
        const bool b = (p == rec.idB) && !a;
        if (a || b) {
            const unsigned i = atomicAdd(&cnt, 1u);
            if (i < 128u) list[i] = (unsigned short)(e | (a ? 0 : 0x8000));
        }
    }
    __syncthreads();

    // ---- gather + LDS max-reduce only the matching pv rows (~70) ----
    const int n = (int)(cnt < 128u ? cnt : 128u);
    for (int k = tid; k < n * NH; k += 256) {
        const int i = k >> 4, d = k & 15;
        const int e = list[i] & 0x7fff;
        unsigned* dst = (list[i] & 0x8000) ? smB : smA;
        atomicMax(dst + d, __float_as_uint(pv[e * NH + d]));
    }
    __syncthreads();

    // ---- 2 threads compute the 2 gates ----
    if (tid < 2) {
        const int bsel = tid ? rec.idB : rec.idA;
        const unsigned* sm = tid ? smB : smA;
        float l0 = bg[0] + gum[bsel * 2 + 0];
        float l1 = bg[1] + gum[bsel * 2 + 1];
#pragma unroll
        for (int k = 0; k < NH; ++k) {
            const float s = __uint_as_float(sm[k]);
            l0 = fmaf(s, Wg[k * 2 + 0], l0);
            l1 = fmaf(s, Wg[k * 2 + 1], l1);
        }
        gAB[tid] = 1.f / (1.f + expf(-(l1 - l0)));   // softmax[:,1], TAU=1
    }
    __syncthreads();

    const float gA = gAB[0];
    const float gB = (rec.idA == rec.idB) ? gAB[0] : gAB[1];

    // ---- scale own 1024 points ----
    const int p0 = (blockIdx.x * 256 + tid) * 4;
    const float4 rv = *reinterpret_cast<const float4*>(refl + p0);
    float4 o;
    o.x = ((p0 + 0) < rec.bpos ? gA : gB) * rv.x;
    o.y = ((p0 + 1) < rec.bpos ? gA : gB) * rv.y;
    o.z = ((p0 + 2) < rec.bpos ? gA : gB) * rv.z;
    o.w = ((p0 + 3) < rec.bpos ? gA : gB) * rv.w;
    *reinterpret_cast<float4*>(out + p0) = o;
}

extern "C" void kernel_launch(void* const* d_in, const int* in_sizes, int n_in,
                              void* d_out, int out_size, void* d_ws, size_t ws_size,
                              hipStream_t stream) {
    const float* pos   = (const float*)d_in[0];
    const float* refl  = (const float*)d_in[1];
    const int*   batch = (const int*)d_in[2];
    const float* gumb  = (const float*)d_in[3];
    const float* W1    = (const float*)d_in[4];
    const float* b1    = (const float*)d_in[5];
    const float* W2    = (const float*)d_in[6];
    const float* b2    = (const float*)d_in[7];
    const float* Wg    = (const float*)d_in[8];
    const float* bg    = (const float*)d_in[9];
    float* out = (float*)d_out;

    // ws layout: pv 128KB | pid 8KB | recs 12KB
    float* pv   = (float*)d_ws;
    int*   pid  = (int*)((char*)d_ws + 131072);
    Rec*   recs = (Rec*)((char*)d_ws + 139264);

    mlp_segmax_kernel<<<NBLK, 256, 0, stream>>>(pos, refl, batch,
                                                W1, b1, W2, b2, pv, pid, recs);
    gate_scale_kernel<<<N_PTS / 1024, 256, 0, stream>>>(refl, pv, pid, recs,
                                                        Wg, bg, gumb, out);
}